// Round 3
// baseline (327.570 us; speedup 1.0000x reference)
//
#include <hip/hip_runtime.h>
#include <hip/hip_bf16.h>
#include <float.h>
#include <math.h>

// B=4, S=4096, D=2048, E=64, K=2
#define B_DIM 4
#define S_DIM 4096
#define D_DIM 2048
#define E_DIM 64
#define N_TOK 16384
#define TOKS 32              // tokens per block
#define NBLK (N_TOK / TOKS)  // 512 blocks (2/CU)
#define NTHR 512             // 8 waves: (token-half g) x (D-slice sl)
#define BK 64                // K per step
#define SLICES 4             // split-K factor
#define DSLICE (D_DIM / SLICES)  // 512
#define KSTEPS (DSLICE / BK)     // 8
#define GAP_THRESH 1e-3f
#define MAXFLAG 16

typedef __bf16 bf16x8_t __attribute__((ext_vector_type(8)));
typedef float f32x4_t __attribute__((ext_vector_type(4)));

union U8 { bf16x8_t v; unsigned short u[8]; };

// truncating fp32 -> (bf16 hi, bf16 lo) split; hi+lo captures ~16 mantissa bits
__device__ __forceinline__ void split2(float f, unsigned short& h, unsigned short& l) {
    unsigned int u = __float_as_uint(f);
    h = (unsigned short)(u >> 16);
    float hf = __uint_as_float(u & 0xFFFF0000u);
    l = (unsigned short)(__float_as_uint(f - hf) >> 16);  // exact residual (Sterbenz)
}

// one-time W -> (hi,lo) bf16 planes in MFMA-fragment order:
//   WS[sl][s][h][t][lane][8], lane = quad*16 + l15
//   element source: expert e = t*16+l15, k = sl*512 + s*64 + h*32 + quad*8 + j
// => a wave's fragment load is base + lane*16B: fully coalesced 1 KB.
// Reads of W are coalesced (thread i covers W[e][k8*8..+8], i = e*256+k8).
// Block 0 also zeros the ws header (zsum, block counter, load sums).
__global__ void wsplit(const float* __restrict__ W, unsigned short* __restrict__ wh,
                       unsigned short* __restrict__ wl, float* __restrict__ wshdr) {
    const int i = blockIdx.x * 256 + threadIdx.x;   // 0..16383
    if (blockIdx.x == 0) { wshdr[threadIdx.x] = 0.f; wshdr[threadIdx.x + 256] = 0.f; }
    const int e    = i >> 8;        // expert row 0..63
    const int k8   = i & 255;       // 8-float chunk 0..255
    const int quad = k8 & 3;
    const int h    = (k8 >> 2) & 1;
    const int s    = (k8 >> 3) & 7;
    const int sl   = k8 >> 6;
    const int t    = e >> 4;
    const int l15  = e & 15;
    const int lane = quad * 16 + l15;
    const size_t f = ((size_t)((sl * 8 + s) * 2 + h) * 4 + t) * 64 + lane;
    float4 a = *(const float4*)(W + (size_t)e * D_DIM + k8 * 8);
    float4 b = *(const float4*)(W + (size_t)e * D_DIM + k8 * 8 + 4);
    ushort4 h0, l0, h1, l1;
    split2(a.x, h0.x, l0.x); split2(a.y, h0.y, l0.y);
    split2(a.z, h0.z, l0.z); split2(a.w, h0.w, l0.w);
    split2(b.x, h1.x, l1.x); split2(b.y, h1.y, l1.y);
    split2(b.z, h1.z, l1.z); split2(b.w, h1.w, l1.w);
    *(ushort4*)(wh + f * 8)     = h0;
    *(ushort4*)(wh + f * 8 + 4) = h1;
    *(ushort4*)(wl + f * 8)     = l0;
    *(ushort4*)(wl + f * 8 + 4) = l1;
}

__global__ __launch_bounds__(NTHR, 4) void router_main(
    const float* __restrict__ x, const float* __restrict__ W,
    const unsigned short* __restrict__ whg, const unsigned short* __restrict__ wlg,
    const float* __restrict__ gamma, const float* __restrict__ beta,
    const float* __restrict__ temperature,
    float* __restrict__ out_rw, float* __restrict__ out_dp,
    float* __restrict__ g_zsum, float* __restrict__ g_load,
    float* __restrict__ out_loss)
{
    __shared__ float part[SLICES][TOKS][E_DIM + 2];   // 33792 B (split-K partials)
    __shared__ float lgt[TOKS][E_DIM + 1];            // logits -> y -> exp(y/T)
    __shared__ float lgm[E_DIM], lbt[E_DIM], loadsum[E_DIM];
    __shared__ float smu[TOKS], srs[TOKS], sinv[TOKS];
    __shared__ int sel1[TOKS], sel2[TOKS];
    __shared__ int ftok[MAXFLAG], fcand[MAXFLAG][3];
    __shared__ int nflag;
    __shared__ int lastflag;
    __shared__ float sv[B_DIM * E_DIM];

    const int tid = threadIdx.x;
    const int tokBase = blockIdx.x * TOKS;
    const int lane = tid & 63;
    const int wv = tid >> 6;       // 0..7
    const int g  = wv & 1;         // token half: tokens g*16 .. g*16+15
    const int sl = wv >> 1;        // D-slice 0..3
    const int l15 = lane & 15;
    const int quad = lane >> 4;

    if (tid == 0) nflag = 0;
    if (tid < E_DIM) { lgm[tid] = gamma[tid]; lbt[tid] = beta[tid]; loadsum[tid] = 0.f; }

    // x per-lane A-fragment base: row = token, col = slice base + quad*8
    const float* xp = x + (size_t)(tokBase + g * 16 + l15) * D_DIM + sl * DSLICE + quad * 8;

    // per-lane W bases in fragment-ordered planes: + sl*32768 + lane*8 elements
    const unsigned short* whb = whg + (size_t)sl * 32768 + lane * 8;
    const unsigned short* wlb = wlg + (size_t)sl * 32768 + lane * 8;

    f32x4_t acc[4];
    #pragma unroll
    for (int t = 0; t < 4; ++t) acc[t] = (f32x4_t){0.f, 0.f, 0.f, 0.f};

    float4 xq[4], xn[4];
    #pragma unroll
    for (int c = 0; c < 2; ++c) {
        xq[c * 2]     = *(const float4*)(xp + c * 32);
        xq[c * 2 + 1] = *(const float4*)(xp + c * 32 + 4);
    }

    // barrier-free K-loop; W fragments are coalesced 16B/lane loads from L2
    for (int s = 0; s < KSTEPS; ++s) {
        const bool more = (s + 1 < KSTEPS);
        // issue all 16 W-fragment loads for this step (offsets 0..3072 from 4 bases)
        const unsigned short* hb = whb + s * 4096;   // h=0 base (elements)
        const unsigned short* lb = wlb + s * 4096;
        bf16x8_t BH0[4], BL0[4], BH1[4], BL1[4];
        #pragma unroll
        for (int t = 0; t < 4; ++t) {
            BH0[t] = *(const bf16x8_t*)(hb + t * 512);
            BL0[t] = *(const bf16x8_t*)(lb + t * 512);
        }
        #pragma unroll
        for (int t = 0; t < 4; ++t) {
            BH1[t] = *(const bf16x8_t*)(hb + 2048 + t * 512);
            BL1[t] = *(const bf16x8_t*)(lb + 2048 + t * 512);
        }
        if (more) {  // prefetch next step's x while W loads fly
            const float* xg = xp + (s + 1) * BK;
            #pragma unroll
            for (int c = 0; c < 2; ++c) {
                xn[c * 2]     = *(const float4*)(xg + c * 32);
                xn[c * 2 + 1] = *(const float4*)(xg + c * 32 + 4);
            }
        }
        // h = 0
        {
            float tf[8] = {xq[0].x, xq[0].y, xq[0].z, xq[0].w,
                           xq[1].x, xq[1].y, xq[1].z, xq[1].w};
            U8 ah, al;
            #pragma unroll
            for (int k = 0; k < 8; ++k) split2(tf[k], ah.u[k], al.u[k]);
            #pragma unroll
            for (int t = 0; t < 4; ++t) {
                acc[t] = __builtin_amdgcn_mfma_f32_16x16x32_bf16(ah.v, BH0[t], acc[t], 0, 0, 0);
                acc[t] = __builtin_amdgcn_mfma_f32_16x16x32_bf16(ah.v, BL0[t], acc[t], 0, 0, 0);
                acc[t] = __builtin_amdgcn_mfma_f32_16x16x32_bf16(al.v, BH0[t], acc[t], 0, 0, 0);
            }
        }
        // h = 1
        {
            float tf[8] = {xq[2].x, xq[2].y, xq[2].z, xq[2].w,
                           xq[3].x, xq[3].y, xq[3].z, xq[3].w};
            U8 ah, al;
            #pragma unroll
            for (int k = 0; k < 8; ++k) split2(tf[k], ah.u[k], al.u[k]);
            #pragma unroll
            for (int t = 0; t < 4; ++t) {
                acc[t] = __builtin_amdgcn_mfma_f32_16x16x32_bf16(ah.v, BH1[t], acc[t], 0, 0, 0);
                acc[t] = __builtin_amdgcn_mfma_f32_16x16x32_bf16(ah.v, BL1[t], acc[t], 0, 0, 0);
                acc[t] = __builtin_amdgcn_mfma_f32_16x16x32_bf16(al.v, BH1[t], acc[t], 0, 0, 0);
            }
        }
        if (more) {
            #pragma unroll
            for (int j = 0; j < 4; ++j) xq[j] = xn[j];
        }
    }

    // phase A: partial acc -> LDS.  C/D: col(n)=lane&15, row(m)=quad*4+reg
    #pragma unroll
    for (int t = 0; t < 4; ++t)
        #pragma unroll
        for (int r = 0; r < 4; ++r)
            part[sl][g * 16 + quad * 4 + r][t * 16 + l15] = acc[t][r];
    __syncthreads();

    // split-K reduction: 4 partials -> logits (fixed pairwise order, deterministic)
    for (int i = tid; i < TOKS * E_DIM; i += NTHR) {
        int r = i >> 6, c = i & 63;
        lgt[r][c] = (part[0][r][c] + part[1][r][c]) + (part[2][r][c] + part[3][r][c]);
    }
    __syncthreads();

    // phase B: waves 0-1 only; 4 lanes per token (quad = expert quarter)
    if (wv < 2) {
        const int tok = wv * 16 + l15;
        const int q = quad;
        const float it = 1.f / (temperature[0] + 1e-6f);
        float s1 = 0.f, s2 = 0.f;
        #pragma unroll
        for (int e = 0; e < 16; ++e) { float v = lgt[tok][q * 16 + e]; s1 += v; s2 += v * v; }
        s1 += __shfl_xor(s1, 16); s1 += __shfl_xor(s1, 32);
        s2 += __shfl_xor(s2, 16); s2 += __shfl_xor(s2, 32);
        const float mu  = s1 * (1.f / 64.f);
        const float var = s2 * (1.f / 64.f) - mu * mu;   // biased, matches ref
        const float rs  = rsqrtf(var + 1e-5f);
        if (q == 0) { smu[tok] = mu; srs[tok] = rs; }

        float m0 = -FLT_MAX, m1 = -FLT_MAX, m2 = -FLT_MAX;
        int   i0 = -1, i1 = -1, i2 = -1;
        float zl = 0.f;
        #pragma unroll
        for (int e = 0; e < 16; ++e) {
            int c = q * 16 + e;
            float y = (lgt[tok][c] - mu) * rs * lgm[c] + lbt[c];
            lgt[tok][c] = y;
            zl += y * y;
            if (y > m0)      { m2 = m1; i2 = i1; m1 = m0; i1 = i0; m0 = y; i0 = c; }
            else if (y > m1) { m2 = m1; i2 = i1; m1 = y; i1 = c; }
            else if (y > m2) { m2 = y; i2 = c; }
        }
        // merge sorted top-3 triples across quad lanes (3+3 merge, low-index tie-break)
        #pragma unroll
        for (int d = 16; d <= 32; d <<= 1) {
            float n0 = __shfl_xor(m0, d), n1 = __shfl_xor(m1, d), n2 = __shfl_xor(m2, d);
            int   j0 = __shfl_xor(i0, d), j1 = __shfl_xor(i1, d), j2 = __shfl_xor(i2, d);
            bool t0 = (m0 > n0) || (m0 == n0 && i0 < j0);
            float r0v = t0 ? m0 : n0; int r0i = t0 ? i0 : j0;
            float A0v = t0 ? m1 : m0; int A0i = t0 ? i1 : i0;
            float A1v = t0 ? m2 : m1; int A1i = t0 ? i2 : i1;
            float B0v = t0 ? n0 : n1; int B0i = t0 ? j0 : j1;
            float B1v = t0 ? n1 : n2; int B1i = t0 ? j1 : j2;
            bool t1 = (A0v > B0v) || (A0v == B0v && A0i < B0i);
            float r1v = t1 ? A0v : B0v; int r1i = t1 ? A0i : B0i;
            float A0w = t1 ? A1v : A0v; int A0j = t1 ? A1i : A0i;
            float B0w = t1 ? B0v : B1v; int B0j = t1 ? B0i : B1i;
            bool t2 = (A0w > B0w) || (A0w == B0w && A0j < B0j);
            float r2v = t2 ? A0w : B0w; int r2i = t2 ? A0j : B0j;
            m0 = r0v; i0 = r0i; m1 = r1v; i1 = r1i; m2 = r2v; i2 = r2i;
        }
        if (q == 0) {
            sel1[tok] = i0; sel2[tok] = i1;
            if (m1 - m2 < GAP_THRESH) {   // rank2/rank3 near-tie -> fp64 fix-up
                int sf = atomicAdd(&nflag, 1);
                if (sf < MAXFLAG) { ftok[sf] = tok; fcand[sf][0] = i0; fcand[sf][1] = i1; fcand[sf][2] = i2; }
            }
        }
        // softmax (store unnormalized exp; scale at write time)
        float es = 0.f;
        #pragma unroll
        for (int e = 0; e < 16; ++e) {
            int c = q * 16 + e;
            float ev = __expf((lgt[tok][c] - m0) * it);
            lgt[tok][c] = ev; es += ev;
        }
        es += __shfl_xor(es, 16); es += __shfl_xor(es, 32);
        if (q == 0) sinv[tok] = 1.f / es;
        // z-loss: full-wave reduce (covers this wave's 16 tokens x 64 experts)
        zl += __shfl_xor(zl, 1); zl += __shfl_xor(zl, 2); zl += __shfl_xor(zl, 4);
        zl += __shfl_xor(zl, 8); zl += __shfl_xor(zl, 16); zl += __shfl_xor(zl, 32);
        if (lane == 0) atomicAdd(g_zsum, zl);
    }
    __syncthreads();

    // phase C: cooperative fp64 re-rank of flagged tokens' top-3 candidates (8 waves)
    const int nf = min(nflag, MAXFLAG);
    for (int f = wv; f < nf; f += 8) {
        const int tk = ftok[f];
        const int c0 = fcand[f][0], c1 = fcand[f][1], c2 = fcand[f][2];
        const float* xr = x + (size_t)(tokBase + tk) * D_DIM;
        const float* w0 = W + (size_t)c0 * D_DIM;
        const float* w1 = W + (size_t)c1 * D_DIM;
        const float* w2 = W + (size_t)c2 * D_DIM;
        double L0 = 0.0, L1 = 0.0, L2 = 0.0;
        for (int i = lane; i < D_DIM; i += 64) {
            double xv = (double)xr[i];
            L0 += xv * (double)w0[i];
            L1 += xv * (double)w1[i];
            L2 += xv * (double)w2[i];
        }
        #pragma unroll
        for (int off = 32; off; off >>= 1) {
            L0 += __shfl_down(L0, off);
            L1 += __shfl_down(L1, off);
            L2 += __shfl_down(L2, off);
        }
        if (lane == 0) {
            double dmu = (double)smu[tk], drs = (double)srs[tk];
            double y0 = (L0 - dmu) * drs * (double)lgm[c0] + (double)lbt[c0];
            double y1 = (L1 - dmu) * drs * (double)lgm[c1] + (double)lbt[c1];
            double y2 = (L2 - dmu) * drs * (double)lgm[c2] + (double)lbt[c2];
            bool g01 = (y0 > y1) || (y0 == y1 && c0 < c1);
            bool g02 = (y0 > y2) || (y0 == y2 && c0 < c2);
            bool g12 = (y1 > y2) || (y1 == y2 && c1 < c2);
            int a, b;
            if (!g01 && !g02)      { a = c1; b = c2; }   // elem0 loses both
            else if (g01 && !g12)  { a = c0; b = c2; }   // elem1 loses both
            else                   { a = c0; b = c1; }   // elem2 loses both
            sel1[tk] = a; sel2[tk] = b;
        }
    }
    __syncthreads();

    // phase D: expert-load accumulation (selection-dependent, post-fix-up)
    if (tid < TOKS) {
        float inv = sinv[tid];
        atomicAdd(&loadsum[sel1[tid]], lgt[tid][sel1[tid]] * inv);
        atomicAdd(&loadsum[sel2[tid]], lgt[tid][sel2[tid]] * inv);
    }
    __syncthreads();
    if (tid < E_DIM) atomicAdd(&g_load[(tokBase >> 12) * E_DIM + tid], loadsum[tid]);

    // phase E: coalesced outputs (8 KB per array per block)
    float* orw = out_rw + (size_t)tokBase * E_DIM;
    float* odp = out_dp + (size_t)tokBase * E_DIM;
    for (int i = tid; i < TOKS * E_DIM; i += NTHR) {
        int r = i >> 6, c = i & 63;
        float p = lgt[r][c] * sinv[r];
        orw[i] = p;
        odp[i] = (c == sel1[r] || c == sel2[r]) ? p : 0.f;
    }

    // phase F: last block computes the loss (folded router_fin; saves a launch)
    __threadfence();
    if (tid == 0) {
        int prev = atomicAdd((int*)(g_zsum + 4), 1);   // header slot 4 = block counter
        lastflag = (prev == NBLK - 1);
    }
    __syncthreads();
    if (lastflag) {
        __threadfence();
        if (tid < B_DIM * E_DIM)   // device-coherent read-back of other blocks' atomics
            sv[tid] = atomicAdd(&g_load[tid], 0.f) * (1.f / S_DIM);
        __syncthreads();
        if (tid == 0) {
            float s = 0.f;
            for (int i = 0; i < B_DIM * E_DIM; ++i) s += sv[i];
            const float mean = s * (1.f / (B_DIM * E_DIM));
            float ss = 0.f;
            for (int i = 0; i < B_DIM * E_DIM; ++i) { float d = sv[i] - mean; ss += d * d; }
            const float sd = sqrtf(ss * (1.f / (B_DIM * E_DIM - 1)));  // ddof=1
            const float z = atomicAdd(g_zsum, 0.f) * (1.f / ((float)N_TOK * E_DIM));
            out_loss[0] = 0.001f * z + 0.1f * (sd / mean) * 10.f;
        }
    }
}

extern "C" void kernel_launch(void* const* d_in, const int* in_sizes, int n_in,
                              void* d_out, int out_size, void* d_ws, size_t ws_size,
                              hipStream_t stream) {
    const float* x     = (const float*)d_in[0];
    const float* W     = (const float*)d_in[1];
    const float* gamma = (const float*)d_in[2];
    const float* beta  = (const float*)d_in[3];
    const float* temp  = (const float*)d_in[4];
    float* out  = (float*)d_out;
    float* rw   = out;                                  // routing_weights [N, E]
    float* dp   = out + (size_t)N_TOK * E_DIM;          // dispatch [B, S, E]
    float* loss = out + 2 * (size_t)N_TOK * E_DIM;      // total_loss scalar
    float* ws   = (float*)d_ws;   // [0]=zsum, [4]=counter, [8..264)=load sums

    // workspace layout: [0,2KB) header | [4KB, +256KB) W-hi frag-order | +256KB W-lo
    unsigned short* whg = (unsigned short*)((char*)d_ws + 4096);
    unsigned short* wlg = whg + (size_t)E_DIM * D_DIM;

    wsplit<<<dim3(64), dim3(256), 0, stream>>>(W, whg, wlg, ws);  // also zeros header
    router_main<<<dim3(NBLK), dim3(NTHR), 0, stream>>>(x, W, whg, wlg, gamma, beta, temp,
                                                       rw, dp, ws, ws + 8, loss);
}

// Round 5
// 287.128 us; speedup vs baseline: 1.1409x; 1.1409x over previous
//
#include <hip/hip_runtime.h>
#include <hip/hip_bf16.h>
#include <float.h>
#include <math.h>

// B=4, S=4096, D=2048, E=64, K=2
#define B_DIM 4
#define S_DIM 4096
#define D_DIM 2048
#define E_DIM 64
#define N_TOK 16384
#define TOKS 32              // tokens per block
#define NBLK (N_TOK / TOKS)  // 512 blocks (2/CU)
#define NTHR 512             // 8 waves: (token-half g) x (D-slice sl)
#define BK 64                // K per step
#define SLICES 4             // split-K factor
#define DSLICE (D_DIM / SLICES)  // 512
#define KSTEPS (DSLICE / BK)     // 8
#define GAP_THRESH 1e-3f
#define MAXFLAG 16

typedef __bf16 bf16x8_t __attribute__((ext_vector_type(8)));
typedef float f32x4_t __attribute__((ext_vector_type(4)));

union U8 { bf16x8_t v; unsigned short u[8]; };

// truncating fp32 -> (bf16 hi, bf16 lo) split; hi+lo captures ~16 mantissa bits
__device__ __forceinline__ void split2(float f, unsigned short& h, unsigned short& l) {
    unsigned int u = __float_as_uint(f);
    h = (unsigned short)(u >> 16);
    float hf = __uint_as_float(u & 0xFFFF0000u);
    l = (unsigned short)(__float_as_uint(f - hf) >> 16);  // exact residual (Sterbenz)
}

// one-time W -> (hi,lo) bf16 planes in MFMA-fragment order (verified in round 3):
//   elem offset = (((sl*8 + s)*2 + h)*4 + t)*512 + lane*8,  lane = quad*16 + l15
//   element source: expert e = t*16+l15, k = sl*512 + s*64 + h*32 + quad*8 + j
// Block 0 also zeros the ws header (zsum, block counter, load sums).
__global__ void wsplit(const float* __restrict__ W, unsigned short* __restrict__ wh,
                       unsigned short* __restrict__ wl, float* __restrict__ wshdr) {
    const int i = blockIdx.x * 256 + threadIdx.x;   // 0..16383
    if (blockIdx.x == 0) { wshdr[threadIdx.x] = 0.f; wshdr[threadIdx.x + 256] = 0.f; }
    const int e    = i >> 8;        // expert row 0..63
    const int k8   = i & 255;       // 8-float chunk 0..255
    const int quad = k8 & 3;
    const int h    = (k8 >> 2) & 1;
    const int s    = (k8 >> 3) & 7;
    const int sl   = k8 >> 6;
    const int t    = e >> 4;
    const int l15  = e & 15;
    const int lane = quad * 16 + l15;
    const size_t f = ((size_t)((sl * 8 + s) * 2 + h) * 4 + t) * 64 + lane;
    float4 a = *(const float4*)(W + (size_t)e * D_DIM + k8 * 8);
    float4 b = *(const float4*)(W + (size_t)e * D_DIM + k8 * 8 + 4);
    ushort4 h0, l0, h1, l1;
    split2(a.x, h0.x, l0.x); split2(a.y, h0.y, l0.y);
    split2(a.z, h0.z, l0.z); split2(a.w, h0.w, l0.w);
    split2(b.x, h1.x, l1.x); split2(b.y, h1.y, l1.y);
    split2(b.z, h1.z, l1.z); split2(b.w, h1.w, l1.w);
    *(ushort4*)(wh + f * 8)     = h0;
    *(ushort4*)(wh + f * 8 + 4) = h1;
    *(ushort4*)(wl + f * 8)     = l0;
    *(ushort4*)(wl + f * 8 + 4) = l1;
}

__global__ __launch_bounds__(NTHR, 4) void router_main(
    const float* __restrict__ x, const float* __restrict__ W,
    const unsigned short* __restrict__ whg, const unsigned short* __restrict__ wlg,
    const float* __restrict__ gamma, const float* __restrict__ beta,
    const float* __restrict__ temperature,
    float* __restrict__ out_rw, float* __restrict__ out_dp,
    float* __restrict__ g_zsum, float* __restrict__ g_load)
{
    // 64 KB arena: W step-tile (hi+lo, frag-order, conflict-free) during the K-loop;
    // split-K partials + logits afterwards (aliased — barrier separates lifetimes).
    __shared__ __align__(16) unsigned char arena[65536];
    unsigned short* const wbufH = (unsigned short*)arena;            // [SLICES][4096]
    unsigned short* const wbufL = (unsigned short*)(arena + 32768);  // [SLICES][4096]
    float (* const part)[TOKS][E_DIM + 2] = (float (*)[TOKS][E_DIM + 2])arena; // [4][32][66]
    float (* const lgt)[E_DIM + 1] = (float (*)[E_DIM + 1])(arena + 33792);    // [32][65]

    __shared__ float lgm[E_DIM], lbt[E_DIM], loadsum[E_DIM];
    __shared__ float smu[TOKS], srs[TOKS], sinv[TOKS];
    __shared__ int sel1[TOKS], sel2[TOKS];
    __shared__ int ftok[MAXFLAG], fcand[MAXFLAG][3];
    __shared__ int nflag;

    const int tid = threadIdx.x;
    const int tokBase = blockIdx.x * TOKS;
    const int lane = tid & 63;
    const int wv = tid >> 6;       // 0..7
    const int g  = wv & 1;         // token half: tokens g*16 .. g*16+15
    const int sl = wv >> 1;        // D-slice 0..3
    const int l15 = lane & 15;
    const int quad = lane >> 4;

    if (tid == 0) nflag = 0;
    if (tid < E_DIM) { lgm[tid] = gamma[tid]; lbt[tid] = beta[tid]; loadsum[tid] = 0.f; }

    // x per-lane A-fragment base: row = token, col = slice base + quad*8
    const float* xp = x + (size_t)(tokBase + g * 16 + l15) * D_DIM + sl * DSLICE + quad * 8;

    // staging: per step s, chunk (k,s) per plane is 4096 contiguous elems (8 KB);
    // thread tid copies elems [tid*8, tid*8+8) of chunk k, both planes.
    const unsigned short* whsrc = whg + tid * 8;   // + k*32768 + s*4096
    const unsigned short* wlsrc = wlg + tid * 8;

    f32x4_t acc[4];
    #pragma unroll
    for (int t = 0; t < 4; ++t) acc[t] = (f32x4_t){0.f, 0.f, 0.f, 0.f};

    // prologue: stage W(0) to LDS, load x(0)
    float4 xq[4], xn[4];
    #pragma unroll
    for (int k = 0; k < SLICES; ++k) {
        uint4 vh = *(const uint4*)(whsrc + k * 32768);
        uint4 vl = *(const uint4*)(wlsrc + k * 32768);
        *(uint4*)(wbufH + k * 4096 + tid * 8) = vh;
        *(uint4*)(wbufL + k * 4096 + tid * 8) = vl;
    }
    #pragma unroll
    for (int c = 0; c < 2; ++c) {
        xq[c * 2]     = *(const float4*)(xp + c * 32);
        xq[c * 2 + 1] = *(const float4*)(xp + c * 32 + 4);
    }
    __syncthreads();

    const unsigned short* hb = wbufH + sl * 4096;   // this wave's slice tile
    const unsigned short* lb = wbufL + sl * 4096;

    for (int s = 0; s < KSTEPS; ++s) {
        const bool more = (s + 1 < KSTEPS);
        uint4 wrh[4], wrl[4];
        if (more) {  // prefetch next step's W (regs) and x (regs) — fly during compute
            #pragma unroll
            for (int k = 0; k < SLICES; ++k) {
                wrh[k] = *(const uint4*)(whsrc + k * 32768 + (s + 1) * 4096);
                wrl[k] = *(const uint4*)(wlsrc + k * 32768 + (s + 1) * 4096);
            }
            const float* xg = xp + (s + 1) * BK;
            #pragma unroll
            for (int c = 0; c < 2; ++c) {
                xn[c * 2]     = *(const float4*)(xg + c * 32);
                xn[c * 2 + 1] = *(const float4*)(xg + c * 32 + 4);
            }
        }
        // compute on staged step s: lane-contiguous ds_read_b128, conflict-free
        #pragma unroll
        for (int h = 0; h < 2; ++h) {
            bf16x8_t bh[4], bl[4];
            #pragma unroll
            for (int t = 0; t < 4; ++t) {
                bh[t] = *(const bf16x8_t*)(hb + (h * 4 + t) * 512 + lane * 8);
                bl[t] = *(const bf16x8_t*)(lb + (h * 4 + t) * 512 + lane * 8);
            }
            float tf[8] = {xq[h*2].x, xq[h*2].y, xq[h*2].z, xq[h*2].w,
                           xq[h*2+1].x, xq[h*2+1].y, xq[h*2+1].z, xq[h*2+1].w};
            U8 ah, al;
            #pragma unroll
            for (int k = 0; k < 8; ++k) split2(tf[k], ah.u[k], al.u[k]);
            #pragma unroll
            for (int t = 0; t < 4; ++t) {
                acc[t] = __builtin_amdgcn_mfma_f32_16x16x32_bf16(ah.v, bh[t], acc[t], 0, 0, 0);
                acc[t] = __builtin_amdgcn_mfma_f32_16x16x32_bf16(ah.v, bl[t], acc[t], 0, 0, 0);
                acc[t] = __builtin_amdgcn_mfma_f32_16x16x32_bf16(al.v, bh[t], acc[t], 0, 0, 0);
            }
        }
        __syncthreads();           // all LDS reads of step s done
        if (more) {                // single-buffered: overwrite with next tile
            #pragma unroll
            for (int k = 0; k < SLICES; ++k) {
                *(uint4*)(wbufH + k * 4096 + tid * 8) = wrh[k];
                *(uint4*)(wbufL + k * 4096 + tid * 8) = wrl[k];
            }
            #pragma unroll
            for (int j = 0; j < 4; ++j) xq[j] = xn[j];
            __syncthreads();       // next tile visible
        }
    }

    // phase A: partial acc -> LDS (wbuf arena dead after loop's final barrier)
    // C/D: col(n)=lane&15, row(m)=quad*4+reg
    #pragma unroll
    for (int t = 0; t < 4; ++t)
        #pragma unroll
        for (int r = 0; r < 4; ++r)
            part[sl][g * 16 + quad * 4 + r][t * 16 + l15] = acc[t][r];
    __syncthreads();

    // split-K reduction: 4 partials -> logits (fixed pairwise order, deterministic)
    for (int i = tid; i < TOKS * E_DIM; i += NTHR) {
        int r = i >> 6, c = i & 63;
        lgt[r][c] = (part[0][r][c] + part[1][r][c]) + (part[2][r][c] + part[3][r][c]);
    }
    __syncthreads();

    // phase B: waves 0-1 only; 4 lanes per token (quad = expert quarter)
    if (wv < 2) {
        const int tok = wv * 16 + l15;
        const int q = quad;
        const float it = 1.f / (temperature[0] + 1e-6f);
        float s1 = 0.f, s2 = 0.f;
        #pragma unroll
        for (int e = 0; e < 16; ++e) { float v = lgt[tok][q * 16 + e]; s1 += v; s2 += v * v; }
        s1 += __shfl_xor(s1, 16); s1 += __shfl_xor(s1, 32);
        s2 += __shfl_xor(s2, 16); s2 += __shfl_xor(s2, 32);
        const float mu  = s1 * (1.f / 64.f);
        const float var = s2 * (1.f / 64.f) - mu * mu;   // biased, matches ref
        const float rs  = rsqrtf(var + 1e-5f);
        if (q == 0) { smu[tok] = mu; srs[tok] = rs; }

        float m0 = -FLT_MAX, m1 = -FLT_MAX, m2 = -FLT_MAX;
        int   i0 = -1, i1 = -1, i2 = -1;
        float zl = 0.f;
        #pragma unroll
        for (int e = 0; e < 16; ++e) {
            int c = q * 16 + e;
            float y = (lgt[tok][c] - mu) * rs * lgm[c] + lbt[c];
            lgt[tok][c] = y;
            zl += y * y;
            if (y > m0)      { m2 = m1; i2 = i1; m1 = m0; i1 = i0; m0 = y; i0 = c; }
            else if (y > m1) { m2 = m1; i2 = i1; m1 = y; i1 = c; }
            else if (y > m2) { m2 = y; i2 = c; }
        }
        // merge sorted top-3 triples across quad lanes (3+3 merge, low-index tie-break)
        #pragma unroll
        for (int d = 16; d <= 32; d <<= 1) {
            float n0 = __shfl_xor(m0, d), n1 = __shfl_xor(m1, d), n2 = __shfl_xor(m2, d);
            int   j0 = __shfl_xor(i0, d), j1 = __shfl_xor(i1, d), j2 = __shfl_xor(i2, d);
            bool t0 = (m0 > n0) || (m0 == n0 && i0 < j0);
            float r0v = t0 ? m0 : n0; int r0i = t0 ? i0 : j0;
            float A0v = t0 ? m1 : m0; int A0i = t0 ? i1 : i0;
            float A1v = t0 ? m2 : m1; int A1i = t0 ? i2 : i1;
            float B0v = t0 ? n0 : n1; int B0i = t0 ? j0 : j1;
            float B1v = t0 ? n1 : n2; int B1i = t0 ? j1 : j2;
            bool t1 = (A0v > B0v) || (A0v == B0v && A0i < B0i);
            float r1v = t1 ? A0v : B0v; int r1i = t1 ? A0i : B0i;
            float A0w = t1 ? A1v : A0v; int A0j = t1 ? A1i : A0i;
            float B0w = t1 ? B0v : B1v; int B0j = t1 ? B0i : B1i;
            bool t2 = (A0w > B0w) || (A0w == B0w && A0j < B0j);
            float r2v = t2 ? A0w : B0w; int r2i = t2 ? A0j : B0j;
            m0 = r0v; i0 = r0i; m1 = r1v; i1 = r1i; m2 = r2v; i2 = r2i;
        }
        if (q == 0) {
            sel1[tok] = i0; sel2[tok] = i1;
            if (m1 - m2 < GAP_THRESH) {   // rank2/rank3 near-tie -> fp64 fix-up
                int sf = atomicAdd(&nflag, 1);
                if (sf < MAXFLAG) { ftok[sf] = tok; fcand[sf][0] = i0; fcand[sf][1] = i1; fcand[sf][2] = i2; }
            }
        }
        // softmax (store unnormalized exp; scale at write time)
        float es = 0.f;
        #pragma unroll
        for (int e = 0; e < 16; ++e) {
            int c = q * 16 + e;
            float ev = __expf((lgt[tok][c] - m0) * it);
            lgt[tok][c] = ev; es += ev;
        }
        es += __shfl_xor(es, 16); es += __shfl_xor(es, 32);
        if (q == 0) sinv[tok] = 1.f / es;
        // z-loss: full-wave reduce (covers this wave's 16 tokens x 64 experts)
        zl += __shfl_xor(zl, 1); zl += __shfl_xor(zl, 2); zl += __shfl_xor(zl, 4);
        zl += __shfl_xor(zl, 8); zl += __shfl_xor(zl, 16); zl += __shfl_xor(zl, 32);
        if (lane == 0) atomicAdd(g_zsum, zl);
    }
    __syncthreads();

    // phase C: cooperative fp64 re-rank of flagged tokens' top-3 candidates (8 waves)
    const int nf = min(nflag, MAXFLAG);
    for (int f = wv; f < nf; f += 8) {
        const int tk = ftok[f];
        const int c0 = fcand[f][0], c1 = fcand[f][1], c2 = fcand[f][2];
        const float* xr = x + (size_t)(tokBase + tk) * D_DIM;
        const float* w0 = W + (size_t)c0 * D_DIM;
        const float* w1 = W + (size_t)c1 * D_DIM;
        const float* w2 = W + (size_t)c2 * D_DIM;
        double L0 = 0.0, L1 = 0.0, L2 = 0.0;
        for (int i = lane; i < D_DIM; i += 64) {
            double xv = (double)xr[i];
            L0 += xv * (double)w0[i];
            L1 += xv * (double)w1[i];
            L2 += xv * (double)w2[i];
        }
        #pragma unroll
        for (int off = 32; off; off >>= 1) {
            L0 += __shfl_down(L0, off);
            L1 += __shfl_down(L1, off);
            L2 += __shfl_down(L2, off);
        }
        if (lane == 0) {
            double dmu = (double)smu[tk], drs = (double)srs[tk];
            double y0 = (L0 - dmu) * drs * (double)lgm[c0] + (double)lbt[c0];
            double y1 = (L1 - dmu) * drs * (double)lgm[c1] + (double)lbt[c1];
            double y2 = (L2 - dmu) * drs * (double)lgm[c2] + (double)lbt[c2];
            bool g01 = (y0 > y1) || (y0 == y1 && c0 < c1);
            bool g02 = (y0 > y2) || (y0 == y2 && c0 < c2);
            bool g12 = (y1 > y2) || (y1 == y2 && c1 < c2);
            int a, b;
            if (!g01 && !g02)      { a = c1; b = c2; }   // elem0 loses both
            else if (g01 && !g12)  { a = c0; b = c2; }   // elem1 loses both
            else                   { a = c0; b = c1; }   // elem2 loses both
            sel1[tk] = a; sel2[tk] = b;
        }
    }
    __syncthreads();

    // phase D: expert-load accumulation (selection-dependent, post-fix-up)
    if (tid < TOKS) {
        float inv = sinv[tid];
        atomicAdd(&loadsum[sel1[tid]], lgt[tid][sel1[tid]] * inv);
        atomicAdd(&loadsum[sel2[tid]], lgt[tid][sel2[tid]] * inv);
    }
    __syncthreads();
    if (tid < E_DIM) atomicAdd(&g_load[(tokBase >> 12) * E_DIM + tid], loadsum[tid]);

    // phase E: coalesced outputs (8 KB per array per block)
    float* orw = out_rw + (size_t)tokBase * E_DIM;
    float* odp = out_dp + (size_t)tokBase * E_DIM;
    for (int i = tid; i < TOKS * E_DIM; i += NTHR) {
        int r = i >> 6, c = i & 63;
        float p = lgt[r][c] * sinv[r];
        orw[i] = p;
        odp[i] = (c == sel1[r] || c == sel2[r]) ? p : 0.f;
    }
}

__global__ void router_fin(const float* __restrict__ ws, float* __restrict__ out_loss) {
    __shared__ float sv[B_DIM * E_DIM];
    const int tid = threadIdx.x;
    sv[tid] = ws[8 + tid] * (1.f / S_DIM);   // expert_load[b][e]
    __syncthreads();
    if (tid == 0) {
        float s = 0.f;
        for (int i = 0; i < B_DIM * E_DIM; ++i) s += sv[i];
        const float mean = s * (1.f / (B_DIM * E_DIM));
        float ss = 0.f;
        for (int i = 0; i < B_DIM * E_DIM; ++i) { float d = sv[i] - mean; ss += d * d; }
        const float sd = sqrtf(ss * (1.f / (B_DIM * E_DIM - 1)));  // ddof=1
        const float z = ws[0] * (1.f / ((float)N_TOK * E_DIM));
        out_loss[0] = 0.001f * z + 0.1f * (sd / mean) * 10.f;
    }
}

extern "C" void kernel_launch(void* const* d_in, const int* in_sizes, int n_in,
                              void* d_out, int out_size, void* d_ws, size_t ws_size,
                              hipStream_t stream) {
    const float* x     = (const float*)d_in[0];
    const float* W     = (const float*)d_in[1];
    const float* gamma = (const float*)d_in[2];
    const float* beta  = (const float*)d_in[3];
    const float* temp  = (const float*)d_in[4];
    float* out  = (float*)d_out;
    float* rw   = out;                                  // routing_weights [N, E]
    float* dp   = out + (size_t)N_TOK * E_DIM;          // dispatch [B, S, E]
    float* loss = out + 2 * (size_t)N_TOK * E_DIM;      // total_loss scalar
    float* ws   = (float*)d_ws;   // [0]=zsum, [8..264)=load sums

    // workspace layout: [0,2KB) header | [4KB, +256KB) W-hi frag-order | +256KB W-lo
    unsigned short* whg = (unsigned short*)((char*)d_ws + 4096);
    unsigned short* wlg = whg + (size_t)E_DIM * D_DIM;

    wsplit<<<dim3(64), dim3(256), 0, stream>>>(W, whg, wlg, ws);  // also zeros header
    router_main<<<dim3(NBLK), dim3(NTHR), 0, stream>>>(x, W, whg, wlg, gamma, beta, temp,
                                                       rw, dp, ws, ws + 8);
    router_fin<<<dim3(1), dim3(256), 0, stream>>>(ws, loss);
}

// Round 6
// 233.149 us; speedup vs baseline: 1.4050x; 1.2315x over previous
//
#include <hip/hip_runtime.h>
#include <hip/hip_bf16.h>
#include <float.h>
#include <math.h>

// B=4, S=4096, D=2048, E=64, K=2
#define B_DIM 4
#define S_DIM 4096
#define D_DIM 2048
#define E_DIM 64
#define N_TOK 16384
#define TOKS 32              // tokens per block
#define NBLK (N_TOK / TOKS)  // 512 blocks (2/CU)
#define NTHR 512             // 8 waves: (token-half g) x (D-slice sl)
#define SLICES 4             // split-K factor
#define DSLICE (D_DIM / SLICES)  // 512
#define KSTEPS2 16           // K=32 per step, double-buffered LDS
#define GAP_THRESH 1e-3f
#define MAXFLAG 16

typedef __bf16 bf16x8_t __attribute__((ext_vector_type(8)));
typedef float f32x4_t __attribute__((ext_vector_type(4)));

union U8 { bf16x8_t v; unsigned short u[8]; };

// truncating fp32 -> (bf16 hi, bf16 lo) split; hi+lo captures ~16 mantissa bits
__device__ __forceinline__ void split2(float f, unsigned short& h, unsigned short& l) {
    unsigned int u = __float_as_uint(f);
    h = (unsigned short)(u >> 16);
    float hf = __uint_as_float(u & 0xFFFF0000u);
    l = (unsigned short)(__float_as_uint(f - hf) >> 16);  // exact residual (Sterbenz)
}

// async 16B global->LDS DMA (no VGPR round-trip, no spill pressure)
typedef const __attribute__((address_space(1))) unsigned int* gas1_t;
typedef __attribute__((address_space(3))) unsigned int* las3_t;
__device__ __forceinline__ void gll16(const unsigned short* g, unsigned short* l) {
    __builtin_amdgcn_global_load_lds((gas1_t)(const void*)g, (las3_t)(void*)l, 16, 0, 0);
}

// one-time W -> (hi,lo) bf16 planes in MFMA-fragment order (verified round 3/5):
//   elem offset = (((sl*8 + s)*2 + h)*4 + t)*512 + lane*8,  lane = quad*16 + l15
//   element source: expert e = t*16+l15, k = sl*512 + s*64 + h*32 + quad*8 + j
// Block 0 also zeros the ws header (zsum, block counter, load sums).
__global__ void wsplit(const float* __restrict__ W, unsigned short* __restrict__ wh,
                       unsigned short* __restrict__ wl, float* __restrict__ wshdr) {
    const int i = blockIdx.x * 256 + threadIdx.x;   // 0..16383
    if (blockIdx.x == 0) { wshdr[threadIdx.x] = 0.f; wshdr[threadIdx.x + 256] = 0.f; }
    const int e    = i >> 8;        // expert row 0..63
    const int k8   = i & 255;       // 8-float chunk 0..255
    const int quad = k8 & 3;
    const int h    = (k8 >> 2) & 1;
    const int s    = (k8 >> 3) & 7;
    const int sl   = k8 >> 6;
    const int t    = e >> 4;
    const int l15  = e & 15;
    const int lane = quad * 16 + l15;
    const size_t f = ((size_t)((sl * 8 + s) * 2 + h) * 4 + t) * 64 + lane;
    float4 a = *(const float4*)(W + (size_t)e * D_DIM + k8 * 8);
    float4 b = *(const float4*)(W + (size_t)e * D_DIM + k8 * 8 + 4);
    ushort4 h0, l0, h1, l1;
    split2(a.x, h0.x, l0.x); split2(a.y, h0.y, l0.y);
    split2(a.z, h0.z, l0.z); split2(a.w, h0.w, l0.w);
    split2(b.x, h1.x, l1.x); split2(b.y, h1.y, l1.y);
    split2(b.z, h1.z, l1.z); split2(b.w, h1.w, l1.w);
    *(ushort4*)(wh + f * 8)     = h0;
    *(ushort4*)(wh + f * 8 + 4) = h1;
    *(ushort4*)(wl + f * 8)     = l0;
    *(ushort4*)(wl + f * 8 + 4) = l1;
}

__global__ __launch_bounds__(NTHR, 4) void router_main(
    const float* __restrict__ x, const float* __restrict__ W,
    const unsigned short* __restrict__ whg, const unsigned short* __restrict__ wlg,
    const float* __restrict__ gamma, const float* __restrict__ beta,
    const float* __restrict__ temperature,
    float* __restrict__ out_rw, float* __restrict__ out_dp,
    float* __restrict__ g_zsum, float* __restrict__ g_load)
{
    // 64 KB arena: double-buffered W step-tiles (hi+lo, frag-order) during the K-loop;
    // split-K partials + logits afterwards (aliased — barrier separates lifetimes).
    __shared__ __align__(16) unsigned char arena[65536];
    unsigned short* const bufH = (unsigned short*)arena;            // [2][4][2048]
    unsigned short* const bufL = (unsigned short*)(arena + 32768);  // [2][4][2048]
    float (* const part)[TOKS][E_DIM + 2] = (float (*)[TOKS][E_DIM + 2])arena; // [4][32][66]
    float (* const lgt)[E_DIM + 1] = (float (*)[E_DIM + 1])(arena + 33792);    // [32][65]

    __shared__ float lgm[E_DIM], lbt[E_DIM], loadsum[E_DIM];
    __shared__ float smu[TOKS], srs[TOKS], sinv[TOKS];
    __shared__ int sel1[TOKS], sel2[TOKS];
    __shared__ int ftok[MAXFLAG], fcand[MAXFLAG][3];
    __shared__ int nflag;

    const int tid = threadIdx.x;
    const int tokBase = blockIdx.x * TOKS;
    const int lane = tid & 63;
    const int wv = tid >> 6;       // 0..7
    const int g  = wv & 1;         // token half: tokens g*16 .. g*16+15
    const int sl = wv >> 1;        // D-slice 0..3
    const int l15 = lane & 15;
    const int quad = lane >> 4;

    if (tid == 0) nflag = 0;
    if (tid < E_DIM) { lgm[tid] = gamma[tid]; lbt[tid] = beta[tid]; loadsum[tid] = 0.f; }

    // x per-lane A-fragment base: row = token, col = slice base + quad*8
    const float* xp = x + (size_t)(tokBase + g * 16 + l15) * D_DIM + sl * DSLICE + quad * 8;

    // DMA staging geometry: per step, per plane, tile = 4 slices x 2048 elems (4 KB each).
    // Thread tid covers slices kk0 and kk0+2 at elem offset soff (16 B per lane, linear):
    // LDS dst = wave-uniform base + lane*16B (matches global_load_lds HW pattern).
    const int kk0  = tid >> 8;            // 0..1
    const int soff = (tid & 255) * 8;

    f32x4_t acc[4];
    #pragma unroll
    for (int t = 0; t < 4; ++t) acc[t] = (f32x4_t){0.f, 0.f, 0.f, 0.f};

#define STAGE(S2, B) do {                                                          \
        const size_t gof = (size_t)(S2) * 2048 + soff;                             \
        unsigned short* hB = bufH + (B) * 8192;                                    \
        unsigned short* lB = bufL + (B) * 8192;                                    \
        gll16(whg + (size_t)kk0 * 32768 + gof,       hB + kk0 * 2048 + soff);      \
        gll16(wlg + (size_t)kk0 * 32768 + gof,       lB + kk0 * 2048 + soff);      \
        gll16(whg + (size_t)(kk0 + 2) * 32768 + gof, hB + (kk0 + 2) * 2048 + soff);\
        gll16(wlg + (size_t)(kk0 + 2) * 32768 + gof, lB + (kk0 + 2) * 2048 + soff);\
    } while (0)

    // prologue: stage step 0 into buf 0, load x(0)
    STAGE(0, 0);
    float4 xq0 = *(const float4*)(xp);
    float4 xq1 = *(const float4*)(xp + 4);
    __syncthreads();   // drains vmcnt: tile 0 staged & visible

    for (int s2 = 0; s2 < KSTEPS2; ++s2) {
        const int cur = s2 & 1;
        const bool more = (s2 + 1 < KSTEPS2);
        float4 xn0, xn1;
        if (more) {   // issue next tile's DMA + x prefetch; they fly under compute
            STAGE(s2 + 1, cur ^ 1);
            xn0 = *(const float4*)(xp + (s2 + 1) * 32);
            xn1 = *(const float4*)(xp + (s2 + 1) * 32 + 4);
        }
        // compute on staged step s2: lane-contiguous ds_read_b128, conflict-free
        const unsigned short* hb = bufH + cur * 8192 + sl * 2048;
        const unsigned short* lb = bufL + cur * 8192 + sl * 2048;
        bf16x8_t bh[4], bl[4];
        #pragma unroll
        for (int t = 0; t < 4; ++t) {
            bh[t] = *(const bf16x8_t*)(hb + t * 512 + lane * 8);
            bl[t] = *(const bf16x8_t*)(lb + t * 512 + lane * 8);
        }
        float tf[8] = {xq0.x, xq0.y, xq0.z, xq0.w, xq1.x, xq1.y, xq1.z, xq1.w};
        U8 ah, al;
        #pragma unroll
        for (int k = 0; k < 8; ++k) split2(tf[k], ah.u[k], al.u[k]);
        #pragma unroll
        for (int t = 0; t < 4; ++t) {
            acc[t] = __builtin_amdgcn_mfma_f32_16x16x32_bf16(ah.v, bh[t], acc[t], 0, 0, 0);
            acc[t] = __builtin_amdgcn_mfma_f32_16x16x32_bf16(ah.v, bl[t], acc[t], 0, 0, 0);
            acc[t] = __builtin_amdgcn_mfma_f32_16x16x32_bf16(al.v, bh[t], acc[t], 0, 0, 0);
        }
        if (more) { xq0 = xn0; xq1 = xn1; }
        __syncthreads();   // next tile staged & this tile's reads done
    }
#undef STAGE

    // phase A: partial acc -> LDS (wbuf arena dead after loop's final barrier)
    // C/D: col(n)=lane&15, row(m)=quad*4+reg
    #pragma unroll
    for (int t = 0; t < 4; ++t)
        #pragma unroll
        for (int r = 0; r < 4; ++r)
            part[sl][g * 16 + quad * 4 + r][t * 16 + l15] = acc[t][r];
    __syncthreads();

    // split-K reduction: 4 partials -> logits (fixed pairwise order, deterministic)
    for (int i = tid; i < TOKS * E_DIM; i += NTHR) {
        int r = i >> 6, c = i & 63;
        lgt[r][c] = (part[0][r][c] + part[1][r][c]) + (part[2][r][c] + part[3][r][c]);
    }
    __syncthreads();

    // phase B: waves 0-1 only; 4 lanes per token (quad = expert quarter)
    if (wv < 2) {
        const int tok = wv * 16 + l15;
        const int q = quad;
        const float it = 1.f / (temperature[0] + 1e-6f);
        float s1 = 0.f, s2 = 0.f;
        #pragma unroll
        for (int e = 0; e < 16; ++e) { float v = lgt[tok][q * 16 + e]; s1 += v; s2 += v * v; }
        s1 += __shfl_xor(s1, 16); s1 += __shfl_xor(s1, 32);
        s2 += __shfl_xor(s2, 16); s2 += __shfl_xor(s2, 32);
        const float mu  = s1 * (1.f / 64.f);
        const float var = s2 * (1.f / 64.f) - mu * mu;   // biased, matches ref
        const float rs  = rsqrtf(var + 1e-5f);
        if (q == 0) { smu[tok] = mu; srs[tok] = rs; }

        float m0 = -FLT_MAX, m1 = -FLT_MAX, m2 = -FLT_MAX;
        int   i0 = -1, i1 = -1, i2 = -1;
        float zl = 0.f;
        #pragma unroll
        for (int e = 0; e < 16; ++e) {
            int c = q * 16 + e;
            float y = (lgt[tok][c] - mu) * rs * lgm[c] + lbt[c];
            lgt[tok][c] = y;
            zl += y * y;
            if (y > m0)      { m2 = m1; i2 = i1; m1 = m0; i1 = i0; m0 = y; i0 = c; }
            else if (y > m1) { m2 = m1; i2 = i1; m1 = y; i1 = c; }
            else if (y > m2) { m2 = y; i2 = c; }
        }
        // merge sorted top-3 triples across quad lanes (3+3 merge, low-index tie-break)
        #pragma unroll
        for (int d = 16; d <= 32; d <<= 1) {
            float n0 = __shfl_xor(m0, d), n1 = __shfl_xor(m1, d), n2 = __shfl_xor(m2, d);
            int   j0 = __shfl_xor(i0, d), j1 = __shfl_xor(i1, d), j2 = __shfl_xor(i2, d);
            bool t0 = (m0 > n0) || (m0 == n0 && i0 < j0);
            float r0v = t0 ? m0 : n0; int r0i = t0 ? i0 : j0;
            float A0v = t0 ? m1 : m0; int A0i = t0 ? i1 : i0;
            float A1v = t0 ? m2 : m1; int A1i = t0 ? i2 : i1;
            float B0v = t0 ? n0 : n1; int B0i = t0 ? j0 : j1;
            float B1v = t0 ? n1 : n2; int B1i = t0 ? j1 : j2;
            bool t1 = (A0v > B0v) || (A0v == B0v && A0i < B0i);
            float r1v = t1 ? A0v : B0v; int r1i = t1 ? A0i : B0i;
            float A0w = t1 ? A1v : A0v; int A0j = t1 ? A1i : A0i;
            float B0w = t1 ? B0v : B1v; int B0j = t1 ? B0i : B1i;
            bool t2 = (A0w > B0w) || (A0w == B0w && A0j < B0j);
            float r2v = t2 ? A0w : B0w; int r2i = t2 ? A0j : B0j;
            m0 = r0v; i0 = r0i; m1 = r1v; i1 = r1i; m2 = r2v; i2 = r2i;
        }
        if (q == 0) {
            sel1[tok] = i0; sel2[tok] = i1;
            if (m1 - m2 < GAP_THRESH) {   // rank2/rank3 near-tie -> fp64 fix-up
                int sf = atomicAdd(&nflag, 1);
                if (sf < MAXFLAG) { ftok[sf] = tok; fcand[sf][0] = i0; fcand[sf][1] = i1; fcand[sf][2] = i2; }
            }
        }
        // softmax (store unnormalized exp; scale at write time)
        float es = 0.f;
        #pragma unroll
        for (int e = 0; e < 16; ++e) {
            int c = q * 16 + e;
            float ev = __expf((lgt[tok][c] - m0) * it);
            lgt[tok][c] = ev; es += ev;
        }
        es += __shfl_xor(es, 16); es += __shfl_xor(es, 32);
        if (q == 0) sinv[tok] = 1.f / es;
        // z-loss: full-wave reduce (covers this wave's 16 tokens x 64 experts)
        zl += __shfl_xor(zl, 1); zl += __shfl_xor(zl, 2); zl += __shfl_xor(zl, 4);
        zl += __shfl_xor(zl, 8); zl += __shfl_xor(zl, 16); zl += __shfl_xor(zl, 32);
        if (lane == 0) atomicAdd(g_zsum, zl);
    }
    __syncthreads();

    // phase C: cooperative fp64 re-rank of flagged tokens' top-3 candidates (8 waves)
    const int nf = min(nflag, MAXFLAG);
    for (int f = wv; f < nf; f += 8) {
        const int tk = ftok[f];
        const int c0 = fcand[f][0], c1 = fcand[f][1], c2 = fcand[f][2];
        const float* xr = x + (size_t)(tokBase + tk) * D_DIM;
        const float* w0 = W + (size_t)c0 * D_DIM;
        const float* w1 = W + (size_t)c1 * D_DIM;
        const float* w2 = W + (size_t)c2 * D_DIM;
        double L0 = 0.0, L1 = 0.0, L2 = 0.0;
        for (int i = lane; i < D_DIM; i += 64) {
            double xv = (double)xr[i];
            L0 += xv * (double)w0[i];
            L1 += xv * (double)w1[i];
            L2 += xv * (double)w2[i];
        }
        #pragma unroll
        for (int off = 32; off; off >>= 1) {
            L0 += __shfl_down(L0, off);
            L1 += __shfl_down(L1, off);
            L2 += __shfl_down(L2, off);
        }
        if (lane == 0) {
            double dmu = (double)smu[tk], drs = (double)srs[tk];
            double y0 = (L0 - dmu) * drs * (double)lgm[c0] + (double)lbt[c0];
            double y1 = (L1 - dmu) * drs * (double)lgm[c1] + (double)lbt[c1];
            double y2 = (L2 - dmu) * drs * (double)lgm[c2] + (double)lbt[c2];
            bool g01 = (y0 > y1) || (y0 == y1 && c0 < c1);
            bool g02 = (y0 > y2) || (y0 == y2 && c0 < c2);
            bool g12 = (y1 > y2) || (y1 == y2 && c1 < c2);
            int a, b;
            if (!g01 && !g02)      { a = c1; b = c2; }   // elem0 loses both
            else if (g01 && !g12)  { a = c0; b = c2; }   // elem1 loses both
            else                   { a = c0; b = c1; }   // elem2 loses both
            sel1[tk] = a; sel2[tk] = b;
        }
    }
    __syncthreads();

    // phase D: expert-load accumulation (selection-dependent, post-fix-up)
    if (tid < TOKS) {
        float inv = sinv[tid];
        atomicAdd(&loadsum[sel1[tid]], lgt[tid][sel1[tid]] * inv);
        atomicAdd(&loadsum[sel2[tid]], lgt[tid][sel2[tid]] * inv);
    }
    __syncthreads();
    if (tid < E_DIM) atomicAdd(&g_load[(tokBase >> 12) * E_DIM + tid], loadsum[tid]);

    // phase E: coalesced outputs (8 KB per array per block)
    float* orw = out_rw + (size_t)tokBase * E_DIM;
    float* odp = out_dp + (size_t)tokBase * E_DIM;
    for (int i = tid; i < TOKS * E_DIM; i += NTHR) {
        int r = i >> 6, c = i & 63;
        float p = lgt[r][c] * sinv[r];
        orw[i] = p;
        odp[i] = (c == sel1[r] || c == sel2[r]) ? p : 0.f;
    }
}

__global__ void router_fin(const float* __restrict__ ws, float* __restrict__ out_loss) {
    __shared__ float sv[B_DIM * E_DIM];
    const int tid = threadIdx.x;
    sv[tid] = ws[8 + tid] * (1.f / S_DIM);   // expert_load[b][e]
    __syncthreads();
    if (tid == 0) {
        float s = 0.f;
        for (int i = 0; i < B_DIM * E_DIM; ++i) s += sv[i];
        const float mean = s * (1.f / (B_DIM * E_DIM));
        float ss = 0.f;
        for (int i = 0; i < B_DIM * E_DIM; ++i) { float d = sv[i] - mean; ss += d * d; }
        const float sd = sqrtf(ss * (1.f / (B_DIM * E_DIM - 1)));  // ddof=1
        const float z = ws[0] * (1.f / ((float)N_TOK * E_DIM));
        out_loss[0] = 0.001f * z + 0.1f * (sd / mean) * 10.f;
    }
}

extern "C" void kernel_launch(void* const* d_in, const int* in_sizes, int n_in,
                              void* d_out, int out_size, void* d_ws, size_t ws_size,
                              hipStream_t stream) {
    const float* x     = (const float*)d_in[0];
    const float* W     = (const float*)d_in[1];
    const float* gamma = (const float*)d_in[2];
    const float* beta  = (const float*)d_in[3];
    const float* temp  = (const float*)d_in[4];
    float* out  = (float*)d_out;
    float* rw   = out;                                  // routing_weights [N, E]
    float* dp   = out + (size_t)N_TOK * E_DIM;          // dispatch [B, S, E]
    float* loss = out + 2 * (size_t)N_TOK * E_DIM;      // total_loss scalar
    float* ws   = (float*)d_ws;   // [0]=zsum, [8..264)=load sums

    // workspace layout: [0,2KB) header | [4KB, +256KB) W-hi frag-order | +256KB W-lo
    unsigned short* whg = (unsigned short*)((char*)d_ws + 4096);
    unsigned short* wlg = whg + (size_t)E_DIM * D_DIM;

    wsplit<<<dim3(64), dim3(256), 0, stream>>>(W, whg, wlg, ws);  // also zeros header
    router_main<<<dim3(NBLK), dim3(NTHR), 0, stream>>>(x, W, whg, wlg, gamma, beta, temp,
                                                       rw, dp, ws, ws + 8);
    router_fin<<<dim3(1), dim3(256), 0, stream>>>(ws, loss);
}

// Round 7
// 226.890 us; speedup vs baseline: 1.4437x; 1.0276x over previous
//
#include <hip/hip_runtime.h>
#include <hip/hip_bf16.h>
#include <float.h>
#include <math.h>

// B=4, S=4096, D=2048, E=64, K=2
#define B_DIM 4
#define S_DIM 4096
#define D_DIM 2048
#define E_DIM 64
#define N_TOK 16384
#define TOKS 32              // tokens per block
#define NBLK (N_TOK / TOKS)  // 512 blocks (2/CU)
#define NTHR 512             // 8 waves: (token-half g) x (D-slice sl)
#define SLICES 4             // split-K factor
#define DSLICE (D_DIM / SLICES)  // 512
#define KSTEPS2 16           // K=32 per step, double-buffered LDS
#define GAP_THRESH 1e-3f
#define MAXFLAG 16

typedef __bf16 bf16x8_t __attribute__((ext_vector_type(8)));
typedef float f32x4_t __attribute__((ext_vector_type(4)));

union U8 { bf16x8_t v; unsigned short u[8]; };

// truncating fp32 -> (bf16 hi, bf16 lo) split; hi+lo captures ~16 mantissa bits
__device__ __forceinline__ void split2(float f, unsigned short& h, unsigned short& l) {
    unsigned int u = __float_as_uint(f);
    h = (unsigned short)(u >> 16);
    float hf = __uint_as_float(u & 0xFFFF0000u);
    l = (unsigned short)(__float_as_uint(f - hf) >> 16);  // exact residual (Sterbenz)
}

// async 16B global->LDS DMA (no VGPR round-trip, no spill pressure)
typedef const __attribute__((address_space(1))) unsigned int* gas1_t;
typedef __attribute__((address_space(3))) unsigned int* las3_t;
__device__ __forceinline__ void gll16(const unsigned short* g, unsigned short* l) {
    __builtin_amdgcn_global_load_lds((gas1_t)(const void*)g, (las3_t)(void*)l, 16, 0, 0);
}

// one-time W -> (hi,lo) bf16 planes in MFMA-fragment order (verified round 3/5/6):
//   elem offset = (((sl*8 + s)*2 + h)*4 + t)*512 + lane*8,  lane = quad*16 + l15
//   element source: expert e = t*16+l15, k = sl*512 + s*64 + h*32 + quad*8 + j
// Block 0 also zeros the ws header (zsum, block counter, load sums).
__global__ void wsplit(const float* __restrict__ W, unsigned short* __restrict__ wh,
                       unsigned short* __restrict__ wl, float* __restrict__ wshdr) {
    const int i = blockIdx.x * 256 + threadIdx.x;   // 0..16383
    if (blockIdx.x == 0) { wshdr[threadIdx.x] = 0.f; wshdr[threadIdx.x + 256] = 0.f; }
    const int e    = i >> 8;        // expert row 0..63
    const int k8   = i & 255;       // 8-float chunk 0..255
    const int quad = k8 & 3;
    const int h    = (k8 >> 2) & 1;
    const int s    = (k8 >> 3) & 7;
    const int sl   = k8 >> 6;
    const int t    = e >> 4;
    const int l15  = e & 15;
    const int lane = quad * 16 + l15;
    const size_t f = ((size_t)((sl * 8 + s) * 2 + h) * 4 + t) * 64 + lane;
    float4 a = *(const float4*)(W + (size_t)e * D_DIM + k8 * 8);
    float4 b = *(const float4*)(W + (size_t)e * D_DIM + k8 * 8 + 4);
    ushort4 h0, l0, h1, l1;
    split2(a.x, h0.x, l0.x); split2(a.y, h0.y, l0.y);
    split2(a.z, h0.z, l0.z); split2(a.w, h0.w, l0.w);
    split2(b.x, h1.x, l1.x); split2(b.y, h1.y, l1.y);
    split2(b.z, h1.z, l1.z); split2(b.w, h1.w, l1.w);
    *(ushort4*)(wh + f * 8)     = h0;
    *(ushort4*)(wh + f * 8 + 4) = h1;
    *(ushort4*)(wl + f * 8)     = l0;
    *(ushort4*)(wl + f * 8 + 4) = l1;
}

__global__ __launch_bounds__(NTHR, 4) void router_main(
    const float* __restrict__ x, const float* __restrict__ W,
    const unsigned short* __restrict__ whg, const unsigned short* __restrict__ wlg,
    const float* __restrict__ gamma, const float* __restrict__ beta,
    const float* __restrict__ temperature,
    float* __restrict__ out_rw, float* __restrict__ out_dp,
    float* __restrict__ g_zsum, float* __restrict__ g_load)
{
    // 64 KB arena: double-buffered W step-tiles (hi+lo, frag-order) during the K-loop;
    // split-K partials + logits afterwards (aliased — barrier separates lifetimes).
    __shared__ __align__(16) unsigned char arena[65536];
    unsigned short* const bufH = (unsigned short*)arena;            // [2][4][2048]
    unsigned short* const bufL = (unsigned short*)(arena + 32768);  // [2][4][2048]
    float (* const part)[TOKS][E_DIM + 2] = (float (*)[TOKS][E_DIM + 2])arena; // [4][32][66]
    float (* const lgt)[E_DIM + 1] = (float (*)[E_DIM + 1])(arena + 33792);    // [32][65]

    __shared__ float lgm[E_DIM], lbt[E_DIM], loadsum[E_DIM];
    __shared__ float smu[TOKS], srs[TOKS], sinv[TOKS];
    __shared__ int sel1[TOKS], sel2[TOKS];
    __shared__ int ftok[MAXFLAG], fcand[MAXFLAG][3];
    __shared__ int nflag;

    const int tid = threadIdx.x;
    const int tokBase = blockIdx.x * TOKS;
    const int lane = tid & 63;
    const int wv = tid >> 6;       // 0..7
    const int g  = wv & 1;         // token half: tokens g*16 .. g*16+15
    const int sl = wv >> 1;        // D-slice 0..3
    const int l15 = lane & 15;
    const int quad = lane >> 4;

    if (tid == 0) nflag = 0;
    if (tid < E_DIM) { lgm[tid] = gamma[tid]; lbt[tid] = beta[tid]; loadsum[tid] = 0.f; }

    // x per-lane A-fragment base: row = token, col = slice base + quad*8
    const float* xp = x + (size_t)(tokBase + g * 16 + l15) * D_DIM + sl * DSLICE + quad * 8;

    // DMA staging geometry: per step, per plane, tile = 4 slices x 2048 elems (4 KB each).
    // Thread tid covers slices kk0 and kk0+2 at elem offset soff (16 B per lane, linear):
    // LDS dst = wave-uniform base + lane*16B (matches global_load_lds HW pattern).
    const int kk0  = tid >> 8;            // 0..1
    const int soff = (tid & 255) * 8;

    f32x4_t acc[4];
    #pragma unroll
    for (int t = 0; t < 4; ++t) acc[t] = (f32x4_t){0.f, 0.f, 0.f, 0.f};

#define STAGE(S2, B) do {                                                          \
        const size_t gof = (size_t)(S2) * 2048 + soff;                             \
        unsigned short* hB = bufH + (B) * 8192;                                    \
        unsigned short* lB = bufL + (B) * 8192;                                    \
        gll16(whg + (size_t)kk0 * 32768 + gof,       hB + kk0 * 2048 + soff);      \
        gll16(wlg + (size_t)kk0 * 32768 + gof,       lB + kk0 * 2048 + soff);      \
        gll16(whg + (size_t)(kk0 + 2) * 32768 + gof, hB + (kk0 + 2) * 2048 + soff);\
        gll16(wlg + (size_t)(kk0 + 2) * 32768 + gof, lB + (kk0 + 2) * 2048 + soff);\
    } while (0)

    // ---- T3+T4 pipelined K-loop: raw barriers + COUNTED vmcnt (never 0) ----
    // Per-wave VMEM issue order (steady state, iter s): [x(s+1) x2] ... [D(s+2) x4].
    // At the post-STAGE wait, ops newer than D(s+1) = x(s+1)(2) + D(s+2)(4) = 6,
    // so vmcnt(6) forces exactly D(s+1) complete while 6 ops stay in flight.
    // prologue: stage tiles 0 and 1, load x(0); wait D(0) (newer: x(0)x2 + D(1)x4 = 6)
    STAGE(0, 0);
    float4 xqA0 = *(const float4*)(xp);
    float4 xqA1 = *(const float4*)(xp + 4);
    STAGE(1, 1);
    asm volatile("s_waitcnt vmcnt(6)" ::: "memory");
    __builtin_amdgcn_sched_barrier(0);
    __builtin_amdgcn_s_barrier();

    float4 xqB0, xqB1;
    #pragma unroll
    for (int s2 = 0; s2 < KSTEPS2; ++s2) {
        const int cur = s2 & 1;
        if (s2 + 1 < KSTEPS2) {   // issue next x load; consumed next iter
            const float* xg = xp + (s2 + 1) * 32;
            xqB0 = *(const float4*)(xg);
            xqB1 = *(const float4*)(xg + 4);
        }
        // compute tile s2 from buf[cur]: lane-contiguous ds_read_b128, conflict-free
        const unsigned short* hb = bufH + cur * 8192 + sl * 2048;
        const unsigned short* lb = bufL + cur * 8192 + sl * 2048;
        bf16x8_t bh[4], bl[4];
        #pragma unroll
        for (int t = 0; t < 4; ++t) {
            bh[t] = *(const bf16x8_t*)(hb + t * 512 + lane * 8);
            bl[t] = *(const bf16x8_t*)(lb + t * 512 + lane * 8);
        }
        float tf[8] = {xqA0.x, xqA0.y, xqA0.z, xqA0.w, xqA1.x, xqA1.y, xqA1.z, xqA1.w};
        U8 ah, al;
        #pragma unroll
        for (int k = 0; k < 8; ++k) split2(tf[k], ah.u[k], al.u[k]);
        #pragma unroll
        for (int t = 0; t < 4; ++t) {
            acc[t] = __builtin_amdgcn_mfma_f32_16x16x32_bf16(ah.v, bh[t], acc[t], 0, 0, 0);
            acc[t] = __builtin_amdgcn_mfma_f32_16x16x32_bf16(ah.v, bl[t], acc[t], 0, 0, 0);
            acc[t] = __builtin_amdgcn_mfma_f32_16x16x32_bf16(al.v, bh[t], acc[t], 0, 0, 0);
        }
        __builtin_amdgcn_s_barrier();          // all waves done reading buf[cur]
        if (s2 + 2 < KSTEPS2) {
            STAGE(s2 + 2, cur);                // refill the just-freed buffer
            asm volatile("s_waitcnt vmcnt(6)" ::: "memory");   // D(s2+1) done
        } else if (s2 + 1 < KSTEPS2) {
            asm volatile("s_waitcnt vmcnt(2)" ::: "memory");   // tail: only x(s2+1) newer
        }
        __builtin_amdgcn_sched_barrier(0);
        __builtin_amdgcn_s_barrier();          // D(s2+1) visible to all waves
        xqA0 = xqB0; xqA1 = xqB1;
    }
#undef STAGE

    __syncthreads();   // loop done (all DMA landed); protect wbuf -> part alias

    // phase A: partial acc -> LDS.  C/D: col(n)=lane&15, row(m)=quad*4+reg
    #pragma unroll
    for (int t = 0; t < 4; ++t)
        #pragma unroll
        for (int r = 0; r < 4; ++r)
            part[sl][g * 16 + quad * 4 + r][t * 16 + l15] = acc[t][r];
    __syncthreads();

    // split-K reduction: 4 partials -> logits (fixed pairwise order, deterministic)
    for (int i = tid; i < TOKS * E_DIM; i += NTHR) {
        int r = i >> 6, c = i & 63;
        lgt[r][c] = (part[0][r][c] + part[1][r][c]) + (part[2][r][c] + part[3][r][c]);
    }
    __syncthreads();

    // phase B: waves 0-1 only; 4 lanes per token (quad = expert quarter)
    if (wv < 2) {
        const int tok = wv * 16 + l15;
        const int q = quad;
        const float it = 1.f / (temperature[0] + 1e-6f);
        float s1 = 0.f, s2 = 0.f;
        #pragma unroll
        for (int e = 0; e < 16; ++e) { float v = lgt[tok][q * 16 + e]; s1 += v; s2 += v * v; }
        s1 += __shfl_xor(s1, 16); s1 += __shfl_xor(s1, 32);
        s2 += __shfl_xor(s2, 16); s2 += __shfl_xor(s2, 32);
        const float mu  = s1 * (1.f / 64.f);
        const float var = s2 * (1.f / 64.f) - mu * mu;   // biased, matches ref
        const float rs  = rsqrtf(var + 1e-5f);
        if (q == 0) { smu[tok] = mu; srs[tok] = rs; }

        float m0 = -FLT_MAX, m1 = -FLT_MAX, m2 = -FLT_MAX;
        int   i0 = -1, i1 = -1, i2 = -1;
        float zl = 0.f;
        #pragma unroll
        for (int e = 0; e < 16; ++e) {
            int c = q * 16 + e;
            float y = (lgt[tok][c] - mu) * rs * lgm[c] + lbt[c];
            lgt[tok][c] = y;
            zl += y * y;
            if (y > m0)      { m2 = m1; i2 = i1; m1 = m0; i1 = i0; m0 = y; i0 = c; }
            else if (y > m1) { m2 = m1; i2 = i1; m1 = y; i1 = c; }
            else if (y > m2) { m2 = y; i2 = c; }
        }
        // merge sorted top-3 triples across quad lanes (3+3 merge, low-index tie-break)
        #pragma unroll
        for (int d = 16; d <= 32; d <<= 1) {
            float n0 = __shfl_xor(m0, d), n1 = __shfl_xor(m1, d), n2 = __shfl_xor(m2, d);
            int   j0 = __shfl_xor(i0, d), j1 = __shfl_xor(i1, d), j2 = __shfl_xor(i2, d);
            bool t0 = (m0 > n0) || (m0 == n0 && i0 < j0);
            float r0v = t0 ? m0 : n0; int r0i = t0 ? i0 : j0;
            float A0v = t0 ? m1 : m0; int A0i = t0 ? i1 : i0;
            float A1v = t0 ? m2 : m1; int A1i = t0 ? i2 : i1;
            float B0v = t0 ? n0 : n1; int B0i = t0 ? j0 : j1;
            float B1v = t0 ? n1 : n2; int B1i = t0 ? j1 : j2;
            bool t1 = (A0v > B0v) || (A0v == B0v && A0i < B0i);
            float r1v = t1 ? A0v : B0v; int r1i = t1 ? A0i : B0i;
            float A0w = t1 ? A1v : A0v; int A0j = t1 ? A1i : A0i;
            float B0w = t1 ? B0v : B1v; int B0j = t1 ? B0i : B1i;
            bool t2 = (A0w > B0w) || (A0w == B0w && A0j < B0j);
            float r2v = t2 ? A0w : B0w; int r2i = t2 ? A0j : B0j;
            m0 = r0v; i0 = r0i; m1 = r1v; i1 = r1i; m2 = r2v; i2 = r2i;
        }
        if (q == 0) {
            sel1[tok] = i0; sel2[tok] = i1;
            if (m1 - m2 < GAP_THRESH) {   // rank2/rank3 near-tie -> fp64 fix-up
                int sf = atomicAdd(&nflag, 1);
                if (sf < MAXFLAG) { ftok[sf] = tok; fcand[sf][0] = i0; fcand[sf][1] = i1; fcand[sf][2] = i2; }
            }
        }
        // softmax (store unnormalized exp; scale at write time)
        float es = 0.f;
        #pragma unroll
        for (int e = 0; e < 16; ++e) {
            int c = q * 16 + e;
            float ev = __expf((lgt[tok][c] - m0) * it);
            lgt[tok][c] = ev; es += ev;
        }
        es += __shfl_xor(es, 16); es += __shfl_xor(es, 32);
        if (q == 0) sinv[tok] = 1.f / es;
        // z-loss: full-wave reduce (covers this wave's 16 tokens x 64 experts)
        zl += __shfl_xor(zl, 1); zl += __shfl_xor(zl, 2); zl += __shfl_xor(zl, 4);
        zl += __shfl_xor(zl, 8); zl += __shfl_xor(zl, 16); zl += __shfl_xor(zl, 32);
        if (lane == 0) atomicAdd(g_zsum, zl);
    }
    __syncthreads();

    // phase C: cooperative fp64 re-rank of flagged tokens' top-3 candidates (8 waves)
    const int nf = min(nflag, MAXFLAG);
    for (int f = wv; f < nf; f += 8) {
        const int tk = ftok[f];
        const int c0 = fcand[f][0], c1 = fcand[f][1], c2 = fcand[f][2];
        const float* xr = x + (size_t)(tokBase + tk) * D_DIM;
        const float* w0 = W + (size_t)c0 * D_DIM;
        const float* w1 = W + (size_t)c1 * D_DIM;
        const float* w2 = W + (size_t)c2 * D_DIM;
        double L0 = 0.0, L1 = 0.0, L2 = 0.0;
        for (int i = lane; i < D_DIM; i += 64) {
            double xv = (double)xr[i];
            L0 += xv * (double)w0[i];
            L1 += xv * (double)w1[i];
            L2 += xv * (double)w2[i];
        }
        #pragma unroll
        for (int off = 32; off; off >>= 1) {
            L0 += __shfl_down(L0, off);
            L1 += __shfl_down(L1, off);
            L2 += __shfl_down(L2, off);
        }
        if (lane == 0) {
            double dmu = (double)smu[tk], drs = (double)srs[tk];
            double y0 = (L0 - dmu) * drs * (double)lgm[c0] + (double)lbt[c0];
            double y1 = (L1 - dmu) * drs * (double)lgm[c1] + (double)lbt[c1];
            double y2 = (L2 - dmu) * drs * (double)lgm[c2] + (double)lbt[c2];
            bool g01 = (y0 > y1) || (y0 == y1 && c0 < c1);
            bool g02 = (y0 > y2) || (y0 == y2 && c0 < c2);
            bool g12 = (y1 > y2) || (y1 == y2 && c1 < c2);
            int a, b;
            if (!g01 && !g02)      { a = c1; b = c2; }   // elem0 loses both
            else if (g01 && !g12)  { a = c0; b = c2; }   // elem1 loses both
            else                   { a = c0; b = c1; }   // elem2 loses both
            sel1[tk] = a; sel2[tk] = b;
        }
    }
    __syncthreads();

    // phase D: expert-load accumulation (selection-dependent, post-fix-up)
    if (tid < TOKS) {
        float inv = sinv[tid];
        atomicAdd(&loadsum[sel1[tid]], lgt[tid][sel1[tid]] * inv);
        atomicAdd(&loadsum[sel2[tid]], lgt[tid][sel2[tid]] * inv);
    }
    __syncthreads();
    if (tid < E_DIM) atomicAdd(&g_load[(tokBase >> 12) * E_DIM + tid], loadsum[tid]);

    // phase E: coalesced outputs (8 KB per array per block)
    float* orw = out_rw + (size_t)tokBase * E_DIM;
    float* odp = out_dp + (size_t)tokBase * E_DIM;
    for (int i = tid; i < TOKS * E_DIM; i += NTHR) {
        int r = i >> 6, c = i & 63;
        float p = lgt[r][c] * sinv[r];
        orw[i] = p;
        odp[i] = (c == sel1[r] || c == sel2[r]) ? p : 0.f;
    }
}

__global__ void router_fin(const float* __restrict__ ws, float* __restrict__ out_loss) {
    __shared__ float sv[B_DIM * E_DIM];
    const int tid = threadIdx.x;
    sv[tid] = ws[8 + tid] * (1.f / S_DIM);   // expert_load[b][e]
    __syncthreads();
    if (tid == 0) {
        float s = 0.f;
        for (int i = 0; i < B_DIM * E_DIM; ++i) s += sv[i];
        const float mean = s * (1.f / (B_DIM * E_DIM));
        float ss = 0.f;
        for (int i = 0; i < B_DIM * E_DIM; ++i) { float d = sv[i] - mean; ss += d * d; }
        const float sd = sqrtf(ss * (1.f / (B_DIM * E_DIM - 1)));  // ddof=1
        const float z = ws[0] * (1.f / ((float)N_TOK * E_DIM));
        out_loss[0] = 0.001f * z + 0.1f * (sd / mean) * 10.f;
    }
}

extern "C" void kernel_launch(void* const* d_in, const int* in_sizes, int n_in,
                              void* d_out, int out_size, void* d_ws, size_t ws_size,
                              hipStream_t stream) {
    const float* x     = (const float*)d_in[0];
    const float* W     = (const float*)d_in[1];
    const float* gamma = (const float*)d_in[2];
    const float* beta  = (const float*)d_in[3];
    const float* temp  = (const float*)d_in[4];
    float* out  = (float*)d_out;
    float* rw   = out;                                  // routing_weights [N, E]
    float* dp   = out + (size_t)N_TOK * E_DIM;          // dispatch [B, S, E]
    float* loss = out + 2 * (size_t)N_TOK * E_DIM;      // total_loss scalar
    float* ws   = (float*)d_ws;   // [0]=zsum, [8..264)=load sums

    // workspace layout: [0,2KB) header | [4KB, +256KB) W-hi frag-order | +256KB W-lo
    unsigned short* whg = (unsigned short*)((char*)d_ws + 4096);
    unsigned short* wlg = whg + (size_t)E_DIM * D_DIM;

    wsplit<<<dim3(64), dim3(256), 0, stream>>>(W, whg, wlg, ws);  // also zeros header
    router_main<<<dim3(NBLK), dim3(NTHR), 0, stream>>>(x, W, whg, wlg, gamma, beta, temp,
                                                       rw, dp, ws, ws + 8);
    router_fin<<<dim3(1), dim3(256), 0, stream>>>(ws, loss);
}